// Round 13
// baseline (49.669 us; speedup 1.0000x reference)
//
#include <hip/hip_runtime.h>

// out[t*768 + e] = weight[e*VOCAB + x[t]]
// memset -> scatter tokens into fixed-cap per-window buckets (64-col windows,
// cap 128, mean 20.9; overflow -> spill list) -> gather: 18864 blocks of 128
// threads, one (32-row, 64-col window) tile each => 16 blocks/CU. Each tile
// reads 256B contiguous per weight row (2x R12's 128B => half the DRAM
// row-activation overhead). Row-major pad-1 LDS (lds[r*65+c]): staging 2-way
// (free), serve conflict-free; serve writes 2 tokens per wave-instr (128B
// coalesced NT stores). Grid/8 = 2358 = 3*786: XCD k owns rows [k*96,+96) =
// contiguous 19MB slice, wids adjacent in time. Blocks 0..63 drain the spill
// list first (no-op on random data).

#define VOCAB 50257
#define EMBED 768
#define WINB 64
#define NWIN 786           // ceil(VOCAB/64); last window has 17 valid cols
#define RG 24              // row groups of 32
#define ROWS 32            // EMBED / RG
#define LSTRIDE 65         // +1 pad: bank=(r+c)%32 -> staging 2-way, serve free
#define CAP 128            // bucket capacity (mean load 20.9)

__global__ __launch_bounds__(256) void scatter_kernel(const int* __restrict__ x,
                                                      int* __restrict__ cur,
                                                      int* __restrict__ buckets,
                                                      int* __restrict__ spill_cnt,
                                                      int* __restrict__ spill,
                                                      int n) {
  int i = blockIdx.x * blockDim.x + threadIdx.x;
  if (i < n) {
    int v = x[i];
    int win = v >> 6;
    int p = atomicAdd(&cur[win], 1);
    if (p < CAP) {
      buckets[win * CAP + p] = (i << 6) | (v & 63);
    } else {
      int s = atomicAdd(spill_cnt, 1);
      spill[s] = (i << 16) | v;       // t:14b | v:16b
    }
  }
}

__device__ __forceinline__ int xcd_swizzle(int bid, int nwg) {
  const int NX = 8;                   // nwg % 8 == 0 -> simple bijection
  int q = nwg / NX;
  return (bid % NX) * q + bid / NX;
}

__global__ __launch_bounds__(128) void gather_kernel(const float* __restrict__ w,
                                                     const int* __restrict__ cur,
                                                     const int* __restrict__ buckets,
                                                     const int* __restrict__ spill_cnt,
                                                     const int* __restrict__ spill,
                                                     float* __restrict__ out) {
  __shared__ float lds[ROWS * LSTRIDE];   // 8.3 KB
  __shared__ int toks[CAP];
  const int tid = threadIdx.x;
  const int b = blockIdx.x;

  // --- adversarial-only spill drain (spill_cnt==0 on random data) ---
  if (b < 64) {
    int cnt = *spill_cnt;
    for (int s = b; s < cnt; s += 64) {
      int pk = spill[s];
      int t = pk >> 16, v = pk & 0xFFFF;
      for (int e = tid; e < EMBED; e += 128)
        out[(size_t)t * EMBED + e] = w[(size_t)e * VOCAB + v];
    }
  }

  const int logical = xcd_swizzle(b, RG * NWIN);
  const int rg  = logical / NWIN;     // XCD k owns rg {3k,3k+1,3k+2}
  const int wid = logical % NWIN;     // adjacent in time within an XCD
  const int row0 = rg * ROWS;
  const int col0 = wid * WINB;

  int pcnt = cur[wid];                // uniform scalar load
  if (tid < CAP) toks[tid] = buckets[wid * CAP + tid];

  // --- stage 32x64 slab row-major: 4 granules (16B) per thread ---
  if (wid != NWIN - 1) {
    #pragma unroll
    for (int k = 0; k < 4; ++k) {
      int j = k * 128 + tid;
      int r = j >> 4, g4 = (j & 15) << 2;
      float4 v = *(const float4*)&w[(size_t)(row0 + r) * VOCAB + col0 + g4];
      float* d = &lds[r * LSTRIDE + g4];    // bank (r+c)%32: 2-way, free
      d[0] = v.x; d[1] = v.y; d[2] = v.z; d[3] = v.w;
    }
  } else {
    #pragma unroll
    for (int k = 0; k < 4; ++k) {
      int j = k * 128 + tid;
      int r = j >> 4, g4 = (j & 15) << 2;
      float* d = &lds[r * LSTRIDE + g4];
      for (int u = 0; u < 4; ++u) {
        int c = col0 + g4 + u;
        d[u] = (c < VOCAB) ? w[(size_t)(row0 + r) * VOCAB + c] : 0.f;
      }
    }
  }
  __syncthreads();

  // --- serve: 2 tokens per wave-instr, 128B-coalesced NT stores ---
  int mcnt = pcnt > CAP ? CAP : pcnt;
  const int wave = tid >> 6;
  const int half = (tid & 63) >> 5;   // 0 or 1: which token of the pair
  const int r = tid & 31;             // row within slab
  for (int i = wave * 2 + half; i < mcnt; i += 4) {
    int pk = toks[i];                 // LDS broadcast
    int t = pk >> 6, c = pk & 63;
    __builtin_nontemporal_store(lds[r * LSTRIDE + c],   // bank r+c: free
                                &out[(size_t)t * EMBED + row0 + r]);
  }
}

extern "C" void kernel_launch(void* const* d_in, const int* in_sizes, int n_in,
                              void* d_out, int out_size, void* d_ws, size_t ws_size,
                              hipStream_t stream) {
  const int*   x = (const int*)d_in[0];
  const float* w = (const float*)d_in[1];
  float* out = (float*)d_out;
  const int n = in_sizes[0];          // 16384 tokens

  int* cur       = (int*)d_ws;        // [NWIN]
  int* spill_cnt = cur + NWIN;        // [1] (contiguous with cur for memset)
  int* spill     = spill_cnt + 1;     // [n]
  int* buckets   = spill + n;         // [NWIN*CAP]

  hipMemsetAsync(cur, 0, (NWIN + 1) * sizeof(int), stream);
  scatter_kernel<<<(n + 255) / 256, 256, 0, stream>>>(x, cur, buckets,
                                                      spill_cnt, spill, n);
  gather_kernel<<<RG * NWIN, 128, 0, stream>>>(w, cur, buckets,
                                               spill_cnt, spill, out);
}

// Round 14
// 46.949 us; speedup vs baseline: 1.0579x; 1.0579x over previous
//
#include <hip/hip_runtime.h>

// out[t*768 + e] = weight[e*VOCAB + x[t]]
// memset -> scatter tokens into fixed-cap per-window buckets (32-col windows,
// cap 64, mean 10.4; overflow -> spill list) -> gather: 25136 blocks of 128
// threads, one (48-row, 32-col window) tile each => 16 blocks/CU. Stage slab
// into TRANSPOSED LDS (lds[c*50+r]: staging writes and serve reads <=2-way,
// free), serve bucket tokens with 192B coalesced stores (A/B vs R12: PLAIN
// stores, not nontemporal -- isolating the NT write-path effect).
// XCD-chunked swizzle: 25136/8 = 2*1571, XCD k owns rows [k*96,+96) =
// contiguous 19MB slice, wids adjacent in time. Blocks 0..63 drain the
// spill list first (no-op on random data).

#define VOCAB 50257
#define EMBED 768
#define WINB 32
#define NWIN 1571          // ceil(VOCAB/32); prime
#define RG 16              // row groups of 48
#define ROWS 48            // EMBED / RG
#define RST 50             // transposed col stride; <=2-way banks everywhere
#define CAP 64             // bucket capacity (mean load 10.4)

__global__ __launch_bounds__(256) void scatter_kernel(const int* __restrict__ x,
                                                      int* __restrict__ cur,
                                                      int* __restrict__ buckets,
                                                      int* __restrict__ spill_cnt,
                                                      int* __restrict__ spill,
                                                      int n) {
  int i = blockIdx.x * blockDim.x + threadIdx.x;
  if (i < n) {
    int v = x[i];
    int win = v >> 5;
    int p = atomicAdd(&cur[win], 1);
    if (p < CAP) {
      buckets[win * CAP + p] = (i << 5) | (v & 31);
    } else {
      int s = atomicAdd(spill_cnt, 1);
      spill[s] = (i << 16) | v;       // t:14b | v:16b
    }
  }
}

__device__ __forceinline__ int xcd_swizzle(int bid, int nwg) {
  const int NX = 8;                   // nwg % 8 == 0 here -> simple bijection
  int q = nwg / NX;
  return (bid % NX) * q + bid / NX;
}

__global__ __launch_bounds__(128) void gather_kernel(const float* __restrict__ w,
                                                     const int* __restrict__ cur,
                                                     const int* __restrict__ buckets,
                                                     const int* __restrict__ spill_cnt,
                                                     const int* __restrict__ spill,
                                                     float* __restrict__ out) {
  __shared__ float lds[WINB * RST];   // 6.4 KB, transposed: lds[c*50 + r]
  __shared__ int toks[CAP];
  const int tid = threadIdx.x;
  const int b = blockIdx.x;

  // --- adversarial-only spill drain (spill_cnt==0 on random data) ---
  if (b < 64) {
    int cnt = *spill_cnt;
    for (int s = b; s < cnt; s += 64) {
      int pk = spill[s];
      int t = pk >> 16, v = pk & 0xFFFF;
      for (int e = tid; e < EMBED; e += 128)
        out[(size_t)t * EMBED + e] = w[(size_t)e * VOCAB + v];
    }
  }

  const int logical = xcd_swizzle(b, RG * NWIN);
  const int rg  = logical / NWIN;     // 0..15; XCD k owns rg {2k, 2k+1}
  const int wid = logical % NWIN;     // adjacent in time within an XCD
  const int row0 = rg * ROWS;
  const int col0 = wid * WINB;

  int pcnt = cur[wid];                // uniform scalar load
  if (tid < CAP) toks[tid] = buckets[wid * CAP + tid];

  // --- stage 48x32 slab transposed: 3 granules/thread ---
  if (wid != NWIN - 1) {
    #pragma unroll
    for (int k = 0; k < 3; ++k) {
      int j = k * 128 + tid;
      int r = j >> 3, g4 = (j & 7) << 2;
      float4 v = *(const float4*)&w[(size_t)(row0 + r) * VOCAB + col0 + g4];
      lds[(g4 + 0) * RST + r] = v.x;  // bank (8g+2u+r)%32 within wave: <=2-way
      lds[(g4 + 1) * RST + r] = v.y;
      lds[(g4 + 2) * RST + r] = v.z;
      lds[(g4 + 3) * RST + r] = v.w;
    }
  } else {
    #pragma unroll
    for (int k = 0; k < 3; ++k) {
      int j = k * 128 + tid;
      int r = j >> 3, g4 = (j & 7) << 2;
      for (int u = 0; u < 4; ++u) {
        int c = col0 + g4 + u;
        lds[(g4 + u) * RST + r] = (c < VOCAB)
            ? w[(size_t)(row0 + r) * VOCAB + c] : 0.f;
      }
    }
  }
  __syncthreads();

  // --- serve bucket tokens; 192B-coalesced PLAIN stores (A/B vs NT) ---
  int mcnt = pcnt > CAP ? CAP : pcnt;
  const int wave = tid >> 6, lane = tid & 63;
  for (int i = wave; i < mcnt; i += 2) {
    int pk = toks[i];                 // LDS broadcast
    int t = pk >> 5, c = pk & 31;
    if (lane < ROWS)                  // reads lds[c*50+lane]: <=2-way, free
      out[(size_t)t * EMBED + row0 + lane] = lds[c * RST + lane];
  }
}

extern "C" void kernel_launch(void* const* d_in, const int* in_sizes, int n_in,
                              void* d_out, int out_size, void* d_ws, size_t ws_size,
                              hipStream_t stream) {
  const int*   x = (const int*)d_in[0];
  const float* w = (const float*)d_in[1];
  float* out = (float*)d_out;
  const int n = in_sizes[0];          // 16384 tokens

  int* cur       = (int*)d_ws;        // [NWIN]
  int* spill_cnt = cur + NWIN;        // [1] (contiguous with cur for memset)
  int* spill     = spill_cnt + 1;     // [n]
  int* buckets   = spill + n;         // [NWIN*CAP]

  hipMemsetAsync(cur, 0, (NWIN + 1) * sizeof(int), stream);
  scatter_kernel<<<(n + 255) / 256, 256, 0, stream>>>(x, cur, buckets,
                                                      spill_cnt, spill, n);
  gather_kernel<<<RG * NWIN, 128, 0, stream>>>(w, cur, buckets,
                                               spill_cnt, spill, out);
}